// Round 11
// baseline (229.966 us; speedup 1.0000x reference)
//
#include <hip/hip_runtime.h>

constexpr int PPB = 128;  // points per block; grid = 1024 (n=131072)
constexpr int N56 = 56*56*64;    // 200704
constexpr int N28 = 28*28*128;   // 100352
constexpr int N14 = 14*14*256;   //  50176
constexpr int N7  = 7*7*512;     //  25088
constexpr int NTOT = N56 + N28 + N14 + N7;       // 376320
constexpr int CONV_BLOCKS = (NTOT + 255) / 256;  // 1470
constexpr int LDS_BYTES  = (N14 + N7) * 2;       // 150528 (f14|f7, contiguous in ws)
constexpr int LDS_CHUNKS = LDS_BYTES / 16;       // 9408

typedef float    f4v __attribute__((ext_vector_type(4)));
typedef _Float16 h4v __attribute__((ext_vector_type(4)));

// ---- fp32 features -> fp16 in d_ws ----
__global__ __launch_bounds__(256) void convert_feats_kernel(
    const float* __restrict__ f56, const float* __restrict__ f28,
    const float* __restrict__ f14, const float* __restrict__ f7,
    _Float16* __restrict__ ws)
{
    int idx = blockIdx.x * 256 + threadIdx.x;
    if (idx >= NTOT) return;
    float v;
    if (idx < N56)              v = f56[idx];
    else if (idx < N56+N28)     v = f28[idx - N56];
    else if (idx < N56+N28+N14) v = f14[idx - (N56+N28)];
    else                        v = f7[idx - (N56+N28+N14)];
    ws[idx] = (_Float16)v;
}

// ---- hot kernel: f14+f7 staged in LDS; 512 threads = 2 points/iter ----
__global__ __launch_bounds__(512) void GraphProjection_57483842289710_kernel(
    const float* __restrict__ coord,
    const _Float16* __restrict__ ws,
    float* __restrict__ out, int n)
{
    extern __shared__ char smem[];   // 150528 B: f14 (100352) | f7 (50176)
    const int t = threadIdx.x;

    // stage the two traffic-dominant levels (contiguous region of ws)
    {
        const f4v* __restrict__ src = reinterpret_cast<const f4v*>(ws + N56 + N28);
        f4v* __restrict__ dst = reinterpret_cast<f4v*>(smem);
        for (int i = t; i < LDS_CHUNKS; i += 512) dst[i] = src[i];
    }
    __syncthreads();

    const int half = t >> 8;    // 0/1: which of the two points this iteration
    const int tt   = t & 255;
    const int ch   = 4 * tt;    // channels ch..ch+3
    const _Float16* sm16 = reinterpret_cast<const _Float16*>(smem);

    // generic pointer: global for levels 0/1, LDS for levels 2/3 (flat loads)
    const _Float16* f; int C, H; float inv;
    if (tt < 16)       { f = ws + ch;              C = 64;  H = 56; inv = 0.25f;    }
    else if (tt < 48)  { f = ws + N56 + (ch - 64); C = 128; H = 28; inv = 0.125f;   }
    else if (tt < 112) { f = sm16 + (ch - 192);    C = 256; H = 14; inv = 0.0625f;  }
    else               { f = sm16 + N14 + (ch-448);C = 512; H = 7;  inv = 0.03125f; }

    const int p0 = blockIdx.x * PPB;

    #pragma unroll 2
    for (int k = 0; k < PPB; k += 2) {
        const int p = p0 + k + half;
        if (p >= n) break;
        float* __restrict__ orow = out + (size_t)p * 963;

        const float X = coord[p * 3 + 0];
        const float Y = coord[p * 3 + 1];
        const float Z = coord[p * 3 + 2];

        const float rz = 1.0f / (-Z);
        float h = 250.0f * (-Y) * rz + 112.0f;
        float w = 250.0f * X  * rz + 112.0f;
        h = fminf(fmaxf(h, 0.0f), 223.0f);
        w = fminf(fmaxf(w, 0.0f), 223.0f);

        if (tt < 240) {
            const float x = h * inv, y = w * inv;
            const float x1 = floorf(x), x2 = ceilf(x);
            const float y1 = floorf(y), y2 = ceilf(y);
            const int xi1 = min(max((int)x1, 0), H - 1);
            const int xi2 = min(max((int)x2, 0), H - 1);
            const int yi1 = min(max((int)y1, 0), H - 1);
            const int yi2 = min(max((int)y2, 0), H - 1);
            const float w11 = (x2 - x) * (y2 - y);
            const float w21 = (x - x1) * (y2 - y);
            const float w12 = (x2 - x) * (y - y1);
            const float w22 = (x - x1) * (y - y1);

            const int r1 = xi1 * H, r2 = xi2 * H;
            const h4v a = *reinterpret_cast<const h4v*>(f + (r1 + yi1) * C);
            const h4v b = *reinterpret_cast<const h4v*>(f + (r2 + yi1) * C);
            const h4v d = *reinterpret_cast<const h4v*>(f + (r1 + yi2) * C);
            const h4v e = *reinterpret_cast<const h4v*>(f + (r2 + yi2) * C);

            f4v r;
            r.x = w11*(float)a.x + w21*(float)b.x + w12*(float)d.x + w22*(float)e.x;
            r.y = w11*(float)a.y + w21*(float)b.y + w12*(float)d.y + w22*(float)e.y;
            r.z = w11*(float)a.z + w21*(float)b.z + w12*(float)d.z + w22*(float)e.z;
            r.w = w11*(float)a.w + w21*(float)b.w + w12*(float)d.w + w22*(float)e.w;
            *reinterpret_cast<f4v*>(orow + 3 + ch) = r;
        } else if (tt < 243) {
            orow[tt - 240] = coord[p * 3 + (tt - 240)];
        }
    }
}

// ---- fallback A: round-7 winner (fp16, no LDS) ----
__global__ __launch_bounds__(256) void proj_f16_inline_kernel(
    const float* __restrict__ coord, const _Float16* __restrict__ ws,
    float* __restrict__ out, int n)
{
    const int t = threadIdx.x;
    const int ch = 4 * t;
    const _Float16* f; int C, H; float inv;
    if (ch < 64)       { f = ws + ch;                     C = 64;  H = 56; inv = 0.25f;    }
    else if (ch < 192) { f = ws + N56 + (ch - 64);        C = 128; H = 28; inv = 0.125f;   }
    else if (ch < 448) { f = ws + N56+N28 + (ch - 192);   C = 256; H = 14; inv = 0.0625f;  }
    else               { f = ws + N56+N28+N14 + (ch-448); C = 512; H = 7;  inv = 0.03125f; }
    const int p0 = blockIdx.x * 16, pend = min(p0 + 16, n);
    #pragma unroll 2
    for (int p = p0; p < pend; ++p) {
        float* __restrict__ orow = out + (size_t)p * 963;
        const float X = coord[p*3+0], Y = coord[p*3+1], Z = coord[p*3+2];
        const float rz = 1.0f / (-Z);
        float h = 250.0f * (-Y) * rz + 112.0f;
        float w = 250.0f * X  * rz + 112.0f;
        h = fminf(fmaxf(h, 0.0f), 223.0f);
        w = fminf(fmaxf(w, 0.0f), 223.0f);
        if (t < 240) {
            const float x = h * inv, y = w * inv;
            const float x1 = floorf(x), x2 = ceilf(x);
            const float y1 = floorf(y), y2 = ceilf(y);
            const int xi1 = min(max((int)x1, 0), H - 1);
            const int xi2 = min(max((int)x2, 0), H - 1);
            const int yi1 = min(max((int)y1, 0), H - 1);
            const int yi2 = min(max((int)y2, 0), H - 1);
            const float w11 = (x2-x)*(y2-y), w21 = (x-x1)*(y2-y);
            const float w12 = (x2-x)*(y-y1), w22 = (x-x1)*(y-y1);
            const int r1 = xi1*H, r2 = xi2*H;
            const h4v a = *reinterpret_cast<const h4v*>(f + (r1+yi1)*C);
            const h4v b = *reinterpret_cast<const h4v*>(f + (r2+yi1)*C);
            const h4v d = *reinterpret_cast<const h4v*>(f + (r1+yi2)*C);
            const h4v e = *reinterpret_cast<const h4v*>(f + (r2+yi2)*C);
            f4v r;
            r.x = w11*(float)a.x + w21*(float)b.x + w12*(float)d.x + w22*(float)e.x;
            r.y = w11*(float)a.y + w21*(float)b.y + w12*(float)d.y + w22*(float)e.y;
            r.z = w11*(float)a.z + w21*(float)b.z + w12*(float)d.z + w22*(float)e.z;
            r.w = w11*(float)a.w + w21*(float)b.w + w12*(float)d.w + w22*(float)e.w;
            *reinterpret_cast<f4v*>(orow + 3 + ch) = r;
        } else if (t < 243) {
            orow[t - 240] = coord[p*3 + (t-240)];
        }
    }
}

// ---- fallback B: fp32 (round-4 winner) ----
__global__ __launch_bounds__(256) void proj_f32_kernel(
    const float* __restrict__ coord,
    const float* __restrict__ f56, const float* __restrict__ f28,
    const float* __restrict__ f14, const float* __restrict__ f7,
    float* __restrict__ out, int n)
{
    const int t = threadIdx.x;
    const int ch = 4 * t;
    const float* f; int C, H; float inv;
    if (ch < 64)       { f = f56 + ch;         C = 64;  H = 56; inv = 0.25f;    }
    else if (ch < 192) { f = f28 + (ch - 64);  C = 128; H = 28; inv = 0.125f;   }
    else if (ch < 448) { f = f14 + (ch - 192); C = 256; H = 14; inv = 0.0625f;  }
    else               { f = f7  + (ch - 448); C = 512; H = 7;  inv = 0.03125f; }
    const int p0 = blockIdx.x * 16, pend = min(p0 + 16, n);
    #pragma unroll 2
    for (int p = p0; p < pend; ++p) {
        float* __restrict__ orow = out + (size_t)p * 963;
        const float X = coord[p*3+0], Y = coord[p*3+1], Z = coord[p*3+2];
        const float rz = 1.0f / (-Z);
        float h = 250.0f * (-Y) * rz + 112.0f;
        float w = 250.0f * X  * rz + 112.0f;
        h = fminf(fmaxf(h, 0.0f), 223.0f);
        w = fminf(fmaxf(w, 0.0f), 223.0f);
        if (t < 240) {
            const float x = h * inv, y = w * inv;
            const float x1 = floorf(x), x2 = ceilf(x);
            const float y1 = floorf(y), y2 = ceilf(y);
            const int xi1 = min(max((int)x1, 0), H - 1);
            const int xi2 = min(max((int)x2, 0), H - 1);
            const int yi1 = min(max((int)y1, 0), H - 1);
            const int yi2 = min(max((int)y2, 0), H - 1);
            const float w11 = (x2-x)*(y2-y), w21 = (x-x1)*(y2-y);
            const float w12 = (x2-x)*(y-y1), w22 = (x-x1)*(y-y1);
            const int r1 = xi1*H, r2 = xi2*H;
            const float4 a = *reinterpret_cast<const float4*>(f + (r1+yi1)*C);
            const float4 b = *reinterpret_cast<const float4*>(f + (r2+yi1)*C);
            const float4 d = *reinterpret_cast<const float4*>(f + (r1+yi2)*C);
            const float4 e = *reinterpret_cast<const float4*>(f + (r2+yi2)*C);
            f4v r;
            r.x = w11*a.x + w21*b.x + w12*d.x + w22*e.x;
            r.y = w11*a.y + w21*b.y + w12*d.y + w22*e.y;
            r.z = w11*a.z + w21*b.z + w12*d.z + w22*e.z;
            r.w = w11*a.w + w21*b.w + w12*d.w + w22*e.w;
            *reinterpret_cast<f4v*>(orow + 3 + ch) = r;
        } else if (t < 243) {
            orow[t - 240] = coord[p*3 + (t-240)];
        }
    }
}

extern "C" void kernel_launch(void* const* d_in, const int* in_sizes, int n_in,
                              void* d_out, int out_size, void* d_ws, size_t ws_size,
                              hipStream_t stream) {
    const float* coord = (const float*)d_in[0];
    const float* f56   = (const float*)d_in[1];
    const float* f28   = (const float*)d_in[2];
    const float* f14   = (const float*)d_in[3];
    const float* f7    = (const float*)d_in[4];
    float* out = (float*)d_out;

    int n = in_sizes[0] / 3;  // 131072 points

    if (ws_size >= (size_t)NTOT * sizeof(_Float16)) {
        _Float16* ws = (_Float16*)d_ws;
        convert_feats_kernel<<<CONV_BLOCKS, 256, 0, stream>>>(f56, f28, f14, f7, ws);

        // allow >64KB dynamic LDS; if unavailable, fall back to no-LDS kernel
        static bool lds_ok = [] {
            return hipFuncSetAttribute(
                (const void*)GraphProjection_57483842289710_kernel,
                hipFuncAttributeMaxDynamicSharedMemorySize, LDS_BYTES) == hipSuccess;
        }();
        if (lds_ok) {
            int grid = (n + PPB - 1) / PPB;  // 1024
            GraphProjection_57483842289710_kernel<<<grid, 512, LDS_BYTES, stream>>>(
                coord, ws, out, n);
        } else {
            int grid = (n + 15) / 16;
            proj_f16_inline_kernel<<<grid, 256, 0, stream>>>(coord, ws, out, n);
        }
    } else {
        int grid = (n + 15) / 16;
        proj_f32_kernel<<<grid, 256, 0, stream>>>(coord, f56, f28, f14, f7, out, n);
    }
}

// Round 12
// 131.644 us; speedup vs baseline: 1.7469x; 1.7469x over previous
//
#include <hip/hip_runtime.h>

constexpr int PPB = 16;  // consecutive points per block (8192 blocks)
constexpr int GRP = 4;   // points staged in LDS per flush (15408 B)
constexpr int N56 = 56*56*64;    // 200704
constexpr int N28 = 28*28*128;   // 100352
constexpr int N14 = 14*14*256;   //  50176
constexpr int N7  = 7*7*512;     //  25088
constexpr int NTOT = N56 + N28 + N14 + N7;       // 376320
constexpr int CONV_BLOCKS = (NTOT + 255) / 256;  // 1470

typedef float    f4v __attribute__((ext_vector_type(4)));
typedef _Float16 h4v __attribute__((ext_vector_type(4)));

// ---- fp32 features -> fp16 in d_ws ----
__global__ __launch_bounds__(256) void convert_feats_kernel(
    const float* __restrict__ f56, const float* __restrict__ f28,
    const float* __restrict__ f14, const float* __restrict__ f7,
    _Float16* __restrict__ ws)
{
    int idx = blockIdx.x * 256 + threadIdx.x;
    if (idx >= NTOT) return;
    float v;
    if (idx < N56)              v = f56[idx];
    else if (idx < N56+N28)     v = f28[idx - N56];
    else if (idx < N56+N28+N14) v = f14[idx - (N56+N28)];
    else                        v = f7[idx - (N56+N28+N14)];
    ws[idx] = (_Float16)v;
}

// ---- hot kernel: R7 compute, output staged in LDS, flushed as aligned
//      full-line nt stores (write stream bypasses L2 -> features stay hot) ----
__global__ __launch_bounds__(256) void GraphProjection_57483842289710_kernel(
    const float* __restrict__ coord,
    const _Float16* __restrict__ ws,
    float* __restrict__ out, int n)
{
    __shared__ float lds[GRP * 963];   // 15412 B -> LDS not occupancy-limiting

    const int t = threadIdx.x;
    const int ch = 4 * t;
    const _Float16* f; int C, H; float inv;
    if (ch < 64)       { f = ws + ch;                     C = 64;  H = 56; inv = 0.25f;    }
    else if (ch < 192) { f = ws + N56 + (ch - 64);        C = 128; H = 28; inv = 0.125f;   }
    else if (ch < 448) { f = ws + N56+N28 + (ch - 192);   C = 256; H = 14; inv = 0.0625f;  }
    else               { f = ws + N56+N28+N14 + (ch-448); C = 512; H = 7;  inv = 0.03125f; }

    const int p0 = blockIdx.x * PPB;

    for (int g = 0; g < PPB / GRP; ++g) {
        const int pg = p0 + g * GRP;

        // ---- phase A: compute GRP points into LDS ----
        #pragma unroll
        for (int k = 0; k < GRP; ++k) {
            const int p = pg + k;
            if (p >= n) break;

            const float X = coord[p * 3 + 0];
            const float Y = coord[p * 3 + 1];
            const float Z = coord[p * 3 + 2];

            const float rz = 1.0f / (-Z);
            float h = 250.0f * (-Y) * rz + 112.0f;
            float w = 250.0f * X  * rz + 112.0f;
            h = fminf(fmaxf(h, 0.0f), 223.0f);
            w = fminf(fmaxf(w, 0.0f), 223.0f);

            if (t < 240) {
                const float x = h * inv, y = w * inv;
                const float x1 = floorf(x), x2 = ceilf(x);
                const float y1 = floorf(y), y2 = ceilf(y);
                const int xi1 = min(max((int)x1, 0), H - 1);
                const int xi2 = min(max((int)x2, 0), H - 1);
                const int yi1 = min(max((int)y1, 0), H - 1);
                const int yi2 = min(max((int)y2, 0), H - 1);
                const float w11 = (x2 - x) * (y2 - y);
                const float w21 = (x - x1) * (y2 - y);
                const float w12 = (x2 - x) * (y - y1);
                const float w22 = (x - x1) * (y - y1);

                const int r1 = xi1 * H, r2 = xi2 * H;
                const h4v a = *reinterpret_cast<const h4v*>(f + (r1 + yi1) * C);
                const h4v b = *reinterpret_cast<const h4v*>(f + (r2 + yi1) * C);
                const h4v d = *reinterpret_cast<const h4v*>(f + (r1 + yi2) * C);
                const h4v e = *reinterpret_cast<const h4v*>(f + (r2 + yi2) * C);

                float* dst = lds + k * 963 + 3 + ch;
                dst[0] = w11*(float)a.x + w21*(float)b.x + w12*(float)d.x + w22*(float)e.x;
                dst[1] = w11*(float)a.y + w21*(float)b.y + w12*(float)d.y + w22*(float)e.y;
                dst[2] = w11*(float)a.z + w21*(float)b.z + w12*(float)d.z + w22*(float)e.z;
                dst[3] = w11*(float)a.w + w21*(float)b.w + w12*(float)d.w + w22*(float)e.w;
            } else if (t < 243) {
                lds[k * 963 + (t - 240)] = coord[p * 3 + (t - 240)];
            }
        }
        __syncthreads();

        // ---- phase B: flush 4 rows (15408 B contiguous) as aligned nt float4 ----
        {
            const f4v* __restrict__ s4 = reinterpret_cast<const f4v*>(lds);
            f4v* __restrict__ d4 = reinterpret_cast<f4v*>(out + (size_t)pg * 963);
            #pragma unroll
            for (int i = t; i < GRP * 963 / 4; i += 256)   // 963 float4s
                __builtin_nontemporal_store(s4[i], d4 + i);
        }
        __syncthreads();
    }
}

// ---- fp32 fallback (round-4 winner) if ws too small ----
__global__ __launch_bounds__(256) void proj_f32_kernel(
    const float* __restrict__ coord,
    const float* __restrict__ f56, const float* __restrict__ f28,
    const float* __restrict__ f14, const float* __restrict__ f7,
    float* __restrict__ out, int n)
{
    const int t = threadIdx.x;
    const int ch = 4 * t;
    const float* f; int C, H; float inv;
    if (ch < 64)       { f = f56 + ch;         C = 64;  H = 56; inv = 0.25f;    }
    else if (ch < 192) { f = f28 + (ch - 64);  C = 128; H = 28; inv = 0.125f;   }
    else if (ch < 448) { f = f14 + (ch - 192); C = 256; H = 14; inv = 0.0625f;  }
    else               { f = f7  + (ch - 448); C = 512; H = 7;  inv = 0.03125f; }
    const int p0 = blockIdx.x * PPB, pend = min(p0 + PPB, n);
    #pragma unroll 2
    for (int p = p0; p < pend; ++p) {
        float* __restrict__ orow = out + (size_t)p * 963;
        const float X = coord[p*3+0], Y = coord[p*3+1], Z = coord[p*3+2];
        const float rz = 1.0f / (-Z);
        float h = 250.0f * (-Y) * rz + 112.0f;
        float w = 250.0f * X  * rz + 112.0f;
        h = fminf(fmaxf(h, 0.0f), 223.0f);
        w = fminf(fmaxf(w, 0.0f), 223.0f);
        if (t < 240) {
            const float x = h * inv, y = w * inv;
            const float x1 = floorf(x), x2 = ceilf(x);
            const float y1 = floorf(y), y2 = ceilf(y);
            const int xi1 = min(max((int)x1, 0), H - 1);
            const int xi2 = min(max((int)x2, 0), H - 1);
            const int yi1 = min(max((int)y1, 0), H - 1);
            const int yi2 = min(max((int)y2, 0), H - 1);
            const float w11 = (x2-x)*(y2-y), w21 = (x-x1)*(y2-y);
            const float w12 = (x2-x)*(y-y1), w22 = (x-x1)*(y-y1);
            const int r1 = xi1*H, r2 = xi2*H;
            const float4 a = *reinterpret_cast<const float4*>(f + (r1+yi1)*C);
            const float4 b = *reinterpret_cast<const float4*>(f + (r2+yi1)*C);
            const float4 d = *reinterpret_cast<const float4*>(f + (r1+yi2)*C);
            const float4 e = *reinterpret_cast<const float4*>(f + (r2+yi2)*C);
            f4v r;
            r.x = w11*a.x + w21*b.x + w12*d.x + w22*e.x;
            r.y = w11*a.y + w21*b.y + w12*d.y + w22*e.y;
            r.z = w11*a.z + w21*b.z + w12*d.z + w22*e.z;
            r.w = w11*a.w + w21*b.w + w12*d.w + w22*e.w;
            *reinterpret_cast<f4v*>(orow + 3 + ch) = r;
        } else if (t < 243) {
            orow[t - 240] = coord[p*3 + (t-240)];
        }
    }
}

extern "C" void kernel_launch(void* const* d_in, const int* in_sizes, int n_in,
                              void* d_out, int out_size, void* d_ws, size_t ws_size,
                              hipStream_t stream) {
    const float* coord = (const float*)d_in[0];
    const float* f56   = (const float*)d_in[1];
    const float* f28   = (const float*)d_in[2];
    const float* f14   = (const float*)d_in[3];
    const float* f7    = (const float*)d_in[4];
    float* out = (float*)d_out;

    int n = in_sizes[0] / 3;  // 131072 points
    int grid = (n + PPB - 1) / PPB;  // 8192

    if (ws_size >= (size_t)NTOT * sizeof(_Float16)) {
        _Float16* ws = (_Float16*)d_ws;
        convert_feats_kernel<<<CONV_BLOCKS, 256, 0, stream>>>(f56, f28, f14, f7, ws);
        GraphProjection_57483842289710_kernel<<<grid, 256, 0, stream>>>(coord, ws, out, n);
    } else {
        proj_f32_kernel<<<grid, 256, 0, stream>>>(coord, f56, f28, f14, f7, out, n);
    }
}